// Round 1
// baseline (656.987 us; speedup 1.0000x reference)
//
#include <hip/hip_runtime.h>
#include <hip/hip_fp16.h>

#define IDIM 512
#define HDIM 512
#define NGATE 2048
#define SEGS 128
#define BATCH 64
#define ZK 0.1f

typedef _Float16 f16;
typedef _Float16 f16x8 __attribute__((ext_vector_type(8)));
typedef float f32x4 __attribute__((ext_vector_type(4)));

__device__ __forceinline__ void gload16(const void* g, void* l) {
  __builtin_amdgcn_global_load_lds((const __attribute__((address_space(1))) void*)g,
                                   (__attribute__((address_space(3))) void*)l, 16, 0, 0);
}
__device__ __forceinline__ float sigmoidf_(float x) { return 1.0f / (1.0f + __expf(-x)); }
__device__ __forceinline__ float tanhf_(float x) { return 2.0f / (1.0f + __expf(-2.0f * x)) - 1.0f; }

// ---------------- prep: starts, counting-sort by dur desc, Mk, mel_len ----------------
__global__ void prep_kernel(const int* __restrict__ durs, int4* __restrict__ meta,
                            int* __restrict__ Mk, int* __restrict__ mel) {
  __shared__ int hist[16];
  __shared__ int cur[16];
  int tid = threadIdx.x;  // 64 threads, one per batch element
  if (tid < 16) hist[tid] = 0;
  __syncthreads();
  int b = tid;
  for (int s = 0; s < SEGS; ++s) {
    int d = durs[s * BATCH + b] & 15;
    atomicAdd(&hist[d], 1);
  }
  __syncthreads();
  if (tid == 0) {
    int run = 0;
    for (int d = 15; d >= 0; --d) { cur[d] = run; run += hist[d]; }
    // Mk[k] = #segments with dur > k  == cur[k]
    for (int kk = 0; kk < 12; ++kk) Mk[kk] = cur[kk];
  }
  __syncthreads();
  int run = 0;
  for (int s = 0; s < SEGS; ++s) {
    int d = durs[s * BATCH + b] & 15;
    int pos = atomicAdd(&cur[d], 1);
    meta[pos] = make_int4(run, b, s, d);  // start, b, s, dur
    run += d;
  }
  mel[b] = run;
}

// ---------------- W prep: permuted combined weight (fp16) + bias ----------------
// permuted row n = 64*(j>>4) + 16*q + (j&15), q in {i,f,g,o}; cols = [W_ih(512) | W_hh(512)]
__global__ void wprep_kernel(const float* __restrict__ Wih, const float* __restrict__ Whh,
                             const float* __restrict__ bih, const float* __restrict__ bhh,
                             f16* __restrict__ Wc, float* __restrict__ biasp) {
  int n = blockIdx.x;
  int G = n >> 6, q = (n >> 4) & 3, r = n & 15;
  int j = G * 16 + r;
  int orig = q * 512 + j;
  for (int kk = threadIdx.x; kk < 1024; kk += blockDim.x) {
    float v = (kk < 512) ? Wih[(size_t)orig * 512 + kk] : Whh[(size_t)orig * 512 + kk - 512];
    Wc[(size_t)n * 1024 + kk] = (f16)v;
  }
  if (threadIdx.x == 0) biasp[n] = bih[orig] + bhh[orig];
}

// ---------------- x: fp32 -> fp16 ----------------
__global__ void xconv_kernel(const float* __restrict__ x, f16* __restrict__ xh, long n8) {
  long i = (long)blockIdx.x * blockDim.x + threadIdx.x;
  long stride = (long)gridDim.x * blockDim.x;
  for (; i < n8; i += stride) {
    const float4* p = (const float4*)(x + i * 8);
    float4 a = p[0], bv = p[1];
    f16x8 o;
    o[0] = (f16)a.x;  o[1] = (f16)a.y;  o[2] = (f16)a.z;  o[3] = (f16)a.w;
    o[4] = (f16)bv.x; o[5] = (f16)bv.y; o[6] = (f16)bv.z; o[7] = (f16)bv.w;
    *(f16x8*)(xh + i * 8) = o;
  }
}

// ---------------- zero: invalid output rows (t >= mel_len[b]) + h + c ----------------
__global__ void zero_kernel(float* __restrict__ out, const int* __restrict__ mel, int T) {
  int bid = blockIdx.x;
  int tb = T * BATCH;
  if (bid < tb) {
    int t = bid / BATCH, b = bid - t * BATCH;
    if (t < mel[b]) return;
    float4* p = (float4*)(out + (size_t)bid * HDIM);
    p[threadIdx.x] = make_float4(0.f, 0.f, 0.f, 0.f);
  } else {
    int e = bid - tb;  // 0..127 : h then c regions (2*B*H floats = 128*512)
    float4* p = (float4*)(out + (size_t)tb * HDIM + (size_t)e * HDIM);
    p[threadIdx.x] = make_float4(0.f, 0.f, 0.f, 0.f);
  }
}

// ---------------- step GEMM + fused LSTM epilogue ----------------
// A (M x K): rows = sorted segments; K = [x_t(512) | h_prev(512)] fp16 (gathered)
// B = Wc (2048 x 1024) fp16, row-major over K (B^T layout for mfma)
template <bool FIRST>
__global__ void step_kernel(const f16* __restrict__ xh, const f16* __restrict__ Wc,
                            const float* __restrict__ biasp,
                            const f16* __restrict__ hprev, f16* __restrict__ hnext,
                            float* __restrict__ cst,
                            const int4* __restrict__ meta, const int* __restrict__ Mk,
                            float* __restrict__ out, int T, int k) {
  const int mk = Mk[k];
  const int m0 = blockIdx.y * 128;
  if (m0 >= mk) return;
  const int n0 = blockIdx.x * 128;

  __shared__ __align__(16) f16 At[128][64];
  __shared__ __align__(16) f16 Bt[128][64];
  __shared__ int4 metaS[128];

  const int tid = threadIdx.x;
  const int lane = tid & 63;
  const int w = tid >> 6;
  const int wr = w >> 1, wc = w & 1;

  if (tid < 128) metaS[tid] = meta[m0 + tid];

  // per-lane staging source pointers (4 global_load_lds per wave per tile)
  const f16* xsrc[4];
  const f16* hsrc[4];
  const f16* wsrc[4];
#pragma unroll
  for (int i = 0; i < 4; ++i) {
    int r = m0 + w * 32 + i * 8 + (lane >> 3);
    int ra = (r < mk) ? r : 0;  // dead rows stage row 0 (safe, masked in epilogue)
    int4 mt = meta[ra];
    xsrc[i] = xh + ((size_t)(mt.x + k) * BATCH + mt.y) * IDIM;
    hsrc[i] = hprev + (size_t)ra * HDIM;
    wsrc[i] = Wc + (size_t)(n0 + w * 32 + i * 8 + (lane >> 3)) * 1024;
  }
  const int koff = (lane & 7) * 8;

  f32x4 acc[4][4];
#pragma unroll
  for (int a = 0; a < 4; ++a)
#pragma unroll
    for (int bb = 0; bb < 4; ++bb) acc[a][bb] = (f32x4){0.f, 0.f, 0.f, 0.f};

  const int KB = FIRST ? 8 : 16;
  for (int kb = 0; kb < KB; ++kb) {
    __syncthreads();
#pragma unroll
    for (int i = 0; i < 4; ++i) {
      const f16* s;
      if (FIRST) s = xsrc[i] + kb * 64 + koff;
      else       s = (kb < 8) ? (xsrc[i] + kb * 64 + koff) : (hsrc[i] + (kb - 8) * 64 + koff);
      gload16(s, &At[w * 32 + i * 8][0]);
    }
#pragma unroll
    for (int i = 0; i < 4; ++i) gload16(wsrc[i] + kb * 64 + koff, &Bt[w * 32 + i * 8][0]);
    __syncthreads();

    const int lr = lane & 15;
    const int lk = (lane >> 4) * 8;
#pragma unroll
    for (int ks = 0; ks < 2; ++ks) {
      f16x8 af[4], bfr[4];
#pragma unroll
      for (int f = 0; f < 4; ++f) af[f] = *(const f16x8*)&At[wr * 64 + f * 16 + lr][ks * 32 + lk];
#pragma unroll
      for (int f = 0; f < 4; ++f) bfr[f] = *(const f16x8*)&Bt[wc * 64 + f * 16 + lr][ks * 32 + lk];
#pragma unroll
      for (int fm = 0; fm < 4; ++fm)
#pragma unroll
        for (int fn = 0; fn < 4; ++fn)
          acc[fm][fn] = __builtin_amdgcn_mfma_f32_16x16x32_f16(af[fm], bfr[fn], acc[fm][fn], 0, 0, 0);
    }
  }

  // ---- fused LSTM epilogue: 4 n-fragments = gates i,f,g,o of h-element j ----
  const int r15 = lane & 15;
  float bq[4];
#pragma unroll
  for (int q = 0; q < 4; ++q) bq[q] = biasp[n0 + wc * 64 + q * 16 + r15];
  const int j = ((n0 + wc * 64) >> 6) * 16 + r15;
  const size_t segoff = (size_t)T * BATCH * HDIM + (size_t)2 * BATCH * HDIM;

#pragma unroll
  for (int fm = 0; fm < 4; ++fm) {
#pragma unroll
    for (int reg = 0; reg < 4; ++reg) {
      int m = m0 + wr * 64 + fm * 16 + ((lane >> 4) << 2) + reg;
      if (m >= mk) continue;
      int4 mt = metaS[m - m0];
      float gi = acc[fm][0][reg] + bq[0];
      float gf = acc[fm][1][reg] + bq[1];
      float gg = acc[fm][2][reg] + bq[2];
      float go = acc[fm][3][reg] + bq[3];
      float iv = sigmoidf_(gi), fv = sigmoidf_(gf);
      float gv = tanhf_(gg), ov = sigmoidf_(go);
      float cp, hp;
      if (FIRST) { cp = 0.f; hp = 0.f; }
      else {
        cp = cst[(size_t)m * HDIM + j];
        hp = (float)hprev[(size_t)m * HDIM + j];
      }
      float cn = fv * cp + iv * gv;
      float hn = ov * tanhf_(cn);
      float hz = ZK * hp + (1.f - ZK) * hn;
      float cz = ZK * cp + (1.f - ZK) * cn;
      out[((size_t)(mt.x + k) * BATCH + mt.y) * HDIM + j] = hz;
      if (k == mt.w - 1) {
        out[segoff + ((size_t)mt.y * SEGS + mt.z) * HDIM + j] = hz;
      } else {
        hnext[(size_t)m * HDIM + j] = (f16)hz;
        cst[(size_t)m * HDIM + j] = cz;
      }
    }
  }
}

extern "C" void kernel_launch(void* const* d_in, const int* in_sizes, int n_in,
                              void* d_out, int out_size, void* d_ws, size_t ws_size,
                              hipStream_t stream) {
  const float* x = (const float*)d_in[0];
  const int* durs = (const int*)d_in[1];
  const float* Wih = (const float*)d_in[2];
  const float* Whh = (const float*)d_in[3];
  const float* bih = (const float*)d_in[4];
  const float* bhh = (const float*)d_in[5];
  float* out = (float*)d_out;
  const int T = in_sizes[0] / (BATCH * IDIM);

  char* ws = (char*)d_ws;
  size_t off = 0;
  auto alloc = [&](size_t bytes) {
    void* p = ws + off;
    off = (off + bytes + 255) & ~(size_t)255;
    return p;
  };
  f16* xh     = (f16*)alloc((size_t)T * BATCH * IDIM * 2);
  f16* Wc     = (f16*)alloc((size_t)NGATE * 1024 * 2);
  float* biasp= (float*)alloc((size_t)NGATE * 4);
  f16* hst0   = (f16*)alloc((size_t)SEGS * BATCH * HDIM * 2);
  f16* hst1   = (f16*)alloc((size_t)SEGS * BATCH * HDIM * 2);
  float* cst  = (float*)alloc((size_t)SEGS * BATCH * HDIM * 4);
  int4* meta  = (int4*)alloc((size_t)SEGS * BATCH * 16);
  int* Mk     = (int*)alloc(64);
  int* mel    = (int*)alloc(64);

  prep_kernel<<<1, 64, 0, stream>>>(durs, meta, Mk, mel);
  wprep_kernel<<<NGATE, 256, 0, stream>>>(Wih, Whh, bih, bhh, Wc, biasp);
  long n8 = (long)T * BATCH * IDIM / 8;
  xconv_kernel<<<2048, 256, 0, stream>>>(x, xh, n8);
  zero_kernel<<<T * BATCH + 128, 128, 0, stream>>>(out, mel, T);

  dim3 sgrid(16, 64);  // x: N/128, y: M/128
  // step 0 writes hst1; step k reads (k&1 ? hst1 : hst0), writes the other
  step_kernel<true><<<sgrid, 256, 0, stream>>>(xh, Wc, biasp, hst0, hst1, cst, meta, Mk, out, T, 0);
  for (int k = 1; k < 12; ++k) {
    f16* hp = (k & 1) ? hst1 : hst0;
    f16* hn = (k & 1) ? hst0 : hst1;
    step_kernel<false><<<sgrid, 256, 0, stream>>>(xh, Wc, biasp, hp, hn, cst, meta, Mk, out, T, k);
  }
}

// Round 2
// 650.128 us; speedup vs baseline: 1.0106x; 1.0106x over previous
//
#include <hip/hip_runtime.h>
#include <hip/hip_fp16.h>

#define IDIM 512
#define HDIM 512
#define NGATE 2048
#define SEGS 128
#define BATCH 64
#define ZK 0.1f

typedef _Float16 f16;
typedef _Float16 f16x8 __attribute__((ext_vector_type(8)));
typedef float f32x4 __attribute__((ext_vector_type(4)));

__device__ __forceinline__ void gload16(const void* g, void* l) {
  __builtin_amdgcn_global_load_lds((const __attribute__((address_space(1))) void*)g,
                                   (__attribute__((address_space(3))) void*)l, 16, 0, 0);
}
__device__ __forceinline__ float sigmoidf_(float x) { return 1.0f / (1.0f + __expf(-x)); }
__device__ __forceinline__ float tanhf_(float x) { return 2.0f / (1.0f + __expf(-2.0f * x)) - 1.0f; }

// ---------------- prep: starts, counting-sort by dur desc, Mk, mel_len ----------------
__global__ void prep_kernel(const int* __restrict__ durs, int4* __restrict__ meta,
                            int* __restrict__ Mk, int* __restrict__ mel) {
  __shared__ int hist[16];
  __shared__ int cur[16];
  int tid = threadIdx.x;  // 64 threads, one per batch element
  if (tid < 16) hist[tid] = 0;
  __syncthreads();
  int b = tid;
  for (int s = 0; s < SEGS; ++s) {
    int d = durs[s * BATCH + b] & 15;
    atomicAdd(&hist[d], 1);
  }
  __syncthreads();
  if (tid == 0) {
    int run = 0;
    for (int d = 15; d >= 0; --d) { cur[d] = run; run += hist[d]; }
    for (int kk = 0; kk < 12; ++kk) Mk[kk] = cur[kk];
  }
  __syncthreads();
  int run = 0;
  for (int s = 0; s < SEGS; ++s) {
    int d = durs[s * BATCH + b] & 15;
    int pos = atomicAdd(&cur[d], 1);
    meta[pos] = make_int4(run, b, s, d);  // start, b, s, dur
    run += d;
  }
  mel[b] = run;
}

// ---------------- W prep: permuted combined weight (fp16) + bias ----------------
__global__ void wprep_kernel(const float* __restrict__ Wih, const float* __restrict__ Whh,
                             const float* __restrict__ bih, const float* __restrict__ bhh,
                             f16* __restrict__ Wc, float* __restrict__ biasp) {
  int n = blockIdx.x;
  int G = n >> 6, q = (n >> 4) & 3, r = n & 15;
  int j = G * 16 + r;
  int orig = q * 512 + j;
  for (int kk = threadIdx.x; kk < 1024; kk += blockDim.x) {
    float v = (kk < 512) ? Wih[(size_t)orig * 512 + kk] : Whh[(size_t)orig * 512 + kk - 512];
    Wc[(size_t)n * 1024 + kk] = (f16)v;
  }
  if (threadIdx.x == 0) biasp[n] = bih[orig] + bhh[orig];
}

// ---------------- x: fp32 -> fp16 ----------------
__global__ void xconv_kernel(const float* __restrict__ x, f16* __restrict__ xh, long n8) {
  long i = (long)blockIdx.x * blockDim.x + threadIdx.x;
  long stride = (long)gridDim.x * blockDim.x;
  for (; i < n8; i += stride) {
    const float4* p = (const float4*)(x + i * 8);
    float4 a = p[0], bv = p[1];
    f16x8 o;
    o[0] = (f16)a.x;  o[1] = (f16)a.y;  o[2] = (f16)a.z;  o[3] = (f16)a.w;
    o[4] = (f16)bv.x; o[5] = (f16)bv.y; o[6] = (f16)bv.z; o[7] = (f16)bv.w;
    *(f16x8*)(xh + i * 8) = o;
  }
}

// ---------------- zero: invalid output rows + h + c ----------------
__global__ void zero_kernel(float* __restrict__ out, const int* __restrict__ mel, int T) {
  int bid = blockIdx.x;
  int tb = T * BATCH;
  if (bid < tb) {
    int t = bid / BATCH, b = bid - t * BATCH;
    if (t < mel[b]) return;
    float4* p = (float4*)(out + (size_t)bid * HDIM);
    p[threadIdx.x] = make_float4(0.f, 0.f, 0.f, 0.f);
  } else {
    int e = bid - tb;
    float4* p = (float4*)(out + (size_t)tb * HDIM + (size_t)e * HDIM);
    p[threadIdx.x] = make_float4(0.f, 0.f, 0.f, 0.f);
  }
}

// ============ HEAD: 256x256xBK64, 8 waves, 4-phase/K-tile, dbuf, T2 swizzle ============
template <bool FIRST>
__global__ __launch_bounds__(512, 1)
void step256_kernel(const f16* __restrict__ xh, const f16* __restrict__ Wc,
                    const float* __restrict__ biasp,
                    const f16* __restrict__ hprev, f16* __restrict__ hnext,
                    float* __restrict__ cst,
                    const int4* __restrict__ meta, const int* __restrict__ Mk,
                    float* __restrict__ out, int T, int k) {
  const int mk = Mk[k];
  // bijective XCD swizzle (nwg = 8*32 = 256, %8==0)
  const int nbx = gridDim.x;
  const int nwg = nbx * gridDim.y;
  const int orig = blockIdx.y * nbx + blockIdx.x;
  const int cpx = nwg >> 3;
  const int swz = (orig & 7) * cpx + (orig >> 3);
  const int by = swz / nbx, bx = swz - by * nbx;
  const int m0 = by * 256;
  if (m0 >= mk) return;
  const int n0 = bx * 256;

  __shared__ __align__(16) f16 As[2][256][64];
  __shared__ __align__(16) f16 Bs[2][256][64];
  __shared__ int4 metaS[256];

  const int tid = threadIdx.x;
  const int lane = tid & 63;
  const int w = tid >> 6;          // 0..7
  const int wr = w >> 2;           // 0..1 : rows wr*128..+128
  const int wc = w & 3;            // 0..3 : cols wc*64..+64
  const int lr = lane & 15;
  const int lk = lane >> 4;        // 0..3

  if (tid < 256) metaS[tid] = meta[m0 + tid];

  // --- staging setup: per-lane gathered sources, pre-swizzled column chunk ---
  const int swzc = (((lane & 7) ^ ((lane >> 3) & 7)) << 3);  // f16 elems within 64-col slice
  size_t xoff[4];
  int ra4[4];
#pragma unroll
  for (int o = 0; o < 4; ++o) {
    int trow = o * 64 + w * 8 + (lane >> 3);
    int r = m0 + trow;
    int ra = (r < mk) ? r : 0;  // dead rows stage row 0 (masked in epilogue)
    int4 mt = meta[ra];
    xoff[o] = ((size_t)(mt.x + k) * BATCH + mt.y) * IDIM + swzc;
    ra4[o] = ra;
  }

  auto stageA = [&](int o, int kb, int slot) {
    const f16* src;
    if (FIRST || kb < 8) src = xh + xoff[o] + kb * 64;
    else src = hprev + (size_t)ra4[o] * HDIM + (kb - 8) * 64 + swzc;
    gload16(src, &As[slot][o * 64 + w * 8][0]);
  };
  auto stageB = [&](int o, int kb, int slot) {
    int trow = o * 64 + w * 8 + (lane >> 3);
    gload16(Wc + (size_t)(n0 + trow) * 1024 + (size_t)kb * 64 + swzc,
            &Bs[slot][o * 64 + w * 8][0]);
  };
  auto stageOp = [&](int idx, int kb, int slot) {
    if (idx < 4) stageA(idx, kb, slot);
    else stageB(idx - 4, kb, slot);
  };

  // --- swizzled fragment reads (conflict-free b128) ---
  auto lda = [&](int slot, int h, int f, int ks) -> f16x8 {
    int row = wr * 128 + h * 64 + f * 16 + lr;
    int ch = (((ks * 4 + lk) ^ (lr & 7)) << 3);
    return *(const f16x8*)&As[slot][row][ch];
  };
  auto ldb = [&](int slot, int q, int ks) -> f16x8 {
    int row = wc * 64 + q * 16 + lr;
    int ch = (((ks * 4 + lk) ^ (lr & 7)) << 3);
    return *(const f16x8*)&Bs[slot][row][ch];
  };

  f32x4 acc[8][4];
#pragma unroll
  for (int a = 0; a < 8; ++a)
#pragma unroll
    for (int bb = 0; bb < 4; ++bb) acc[a][bb] = (f32x4){0.f, 0.f, 0.f, 0.f};

  // prologue: stage K-tile 0 into slot 0, drain, barrier
#pragma unroll
  for (int idx = 0; idx < 8; ++idx) stageOp(idx, 0, 0);
  asm volatile("s_waitcnt vmcnt(0)" ::: "memory");
  __builtin_amdgcn_s_barrier();

  const int KB = FIRST ? 8 : 16;
  f16x8 aF[4][2], bF[4][2];

  for (int kt = 0; kt < KB; ++kt) {
    const int s = kt & 1;
    const int sn = s ^ 1;
    const int kn = kt + 1;
    const bool st = (kn < KB);

    // ---- phase 0: read A-half0 + all B, stage 3 ops, MFMA quad (h0, fn0-1) ----
#pragma unroll
    for (int f = 0; f < 4; ++f)
#pragma unroll
      for (int ks = 0; ks < 2; ++ks) aF[f][ks] = lda(s, 0, f, ks);
#pragma unroll
    for (int q = 0; q < 4; ++q)
#pragma unroll
      for (int ks = 0; ks < 2; ++ks) bF[q][ks] = ldb(s, q, ks);
    if (st) { stageOp(0, kn, sn); stageOp(1, kn, sn); stageOp(2, kn, sn); }
    __builtin_amdgcn_s_barrier();
    __builtin_amdgcn_s_setprio(1);
#pragma unroll
    for (int f = 0; f < 4; ++f)
#pragma unroll
      for (int fn = 0; fn < 2; ++fn)
#pragma unroll
        for (int ks = 0; ks < 2; ++ks)
          acc[f][fn] = __builtin_amdgcn_mfma_f32_16x16x32_f16(aF[f][ks], bF[fn][ks], acc[f][fn], 0, 0, 0);
    __builtin_amdgcn_s_setprio(0);
    __builtin_amdgcn_s_barrier();

    // ---- phase 1: stage 3 ops, MFMA quad (h0, fn2-3) ----
    if (st) { stageOp(3, kn, sn); stageOp(4, kn, sn); stageOp(5, kn, sn); }
    __builtin_amdgcn_s_barrier();
    __builtin_amdgcn_s_setprio(1);
#pragma unroll
    for (int f = 0; f < 4; ++f)
#pragma unroll
      for (int fn = 2; fn < 4; ++fn)
#pragma unroll
        for (int ks = 0; ks < 2; ++ks)
          acc[f][fn] = __builtin_amdgcn_mfma_f32_16x16x32_f16(aF[f][ks], bF[fn][ks], acc[f][fn], 0, 0, 0);
    __builtin_amdgcn_s_setprio(0);
    __builtin_amdgcn_s_barrier();

    // ---- phase 2: read A-half1, stage 2 ops, MFMA quad (h1, fn0-1) ----
#pragma unroll
    for (int f = 0; f < 4; ++f)
#pragma unroll
      for (int ks = 0; ks < 2; ++ks) aF[f][ks] = lda(s, 1, f, ks);
    if (st) { stageOp(6, kn, sn); stageOp(7, kn, sn); }
    __builtin_amdgcn_s_barrier();
    __builtin_amdgcn_s_setprio(1);
#pragma unroll
    for (int f = 0; f < 4; ++f)
#pragma unroll
      for (int fn = 0; fn < 2; ++fn)
#pragma unroll
        for (int ks = 0; ks < 2; ++ks)
          acc[4 + f][fn] = __builtin_amdgcn_mfma_f32_16x16x32_f16(aF[f][ks], bF[fn][ks], acc[4 + f][fn], 0, 0, 0);
    __builtin_amdgcn_s_setprio(0);
    __builtin_amdgcn_s_barrier();

    // ---- phase 3: MFMA quad (h1, fn2-3), then tile boundary ----
    __builtin_amdgcn_s_setprio(1);
#pragma unroll
    for (int f = 0; f < 4; ++f)
#pragma unroll
      for (int fn = 2; fn < 4; ++fn)
#pragma unroll
        for (int ks = 0; ks < 2; ++ks)
          acc[4 + f][fn] = __builtin_amdgcn_mfma_f32_16x16x32_f16(aF[f][ks], bF[fn][ks], acc[4 + f][fn], 0, 0, 0);
    __builtin_amdgcn_s_setprio(0);
    asm volatile("s_waitcnt vmcnt(0)" ::: "memory");  // next tile landed (issued >=2 phases ago)
    __builtin_amdgcn_s_barrier();
  }

  // ---- fused LSTM epilogue ----
  float bq[4];
#pragma unroll
  for (int q = 0; q < 4; ++q) bq[q] = biasp[n0 + wc * 64 + q * 16 + lr];
  const int j = ((n0 + wc * 64) >> 6) * 16 + lr;
  const size_t segoff = (size_t)T * BATCH * HDIM + (size_t)2 * BATCH * HDIM;

#pragma unroll
  for (int fm = 0; fm < 8; ++fm) {
#pragma unroll
    for (int reg = 0; reg < 4; ++reg) {
      int m = m0 + wr * 128 + fm * 16 + ((lane >> 4) << 2) + reg;
      if (m >= mk) continue;
      int4 mt = metaS[m - m0];
      float gi = acc[fm][0][reg] + bq[0];
      float gf = acc[fm][1][reg] + bq[1];
      float gg = acc[fm][2][reg] + bq[2];
      float go = acc[fm][3][reg] + bq[3];
      float iv = sigmoidf_(gi), fv = sigmoidf_(gf);
      float gv = tanhf_(gg), ov = sigmoidf_(go);
      float cp, hp;
      if (FIRST) { cp = 0.f; hp = 0.f; }
      else {
        cp = cst[(size_t)m * HDIM + j];
        hp = (float)hprev[(size_t)m * HDIM + j];
      }
      float cn = fv * cp + iv * gv;
      float hn = ov * tanhf_(cn);
      float hz = ZK * hp + (1.f - ZK) * hn;
      float cz = ZK * cp + (1.f - ZK) * cn;
      out[((size_t)(mt.x + k) * BATCH + mt.y) * HDIM + j] = hz;
      if (k == mt.w - 1) {
        out[segoff + ((size_t)mt.y * SEGS + mt.z) * HDIM + j] = hz;
      } else {
        hnext[(size_t)m * HDIM + j] = (f16)hz;
        cst[(size_t)m * HDIM + j] = cz;
      }
    }
  }
}

// ============ TAIL: proven 128x128 4-wave kernel (unchanged) ============
template <bool FIRST>
__global__ void step_kernel(const f16* __restrict__ xh, const f16* __restrict__ Wc,
                            const float* __restrict__ biasp,
                            const f16* __restrict__ hprev, f16* __restrict__ hnext,
                            float* __restrict__ cst,
                            const int4* __restrict__ meta, const int* __restrict__ Mk,
                            float* __restrict__ out, int T, int k) {
  const int mk = Mk[k];
  const int m0 = blockIdx.y * 128;
  if (m0 >= mk) return;
  const int n0 = blockIdx.x * 128;

  __shared__ __align__(16) f16 At[128][64];
  __shared__ __align__(16) f16 Bt[128][64];
  __shared__ int4 metaS[128];

  const int tid = threadIdx.x;
  const int lane = tid & 63;
  const int w = tid >> 6;
  const int wr = w >> 1, wc = w & 1;

  if (tid < 128) metaS[tid] = meta[m0 + tid];

  const f16* xsrc[4];
  const f16* hsrc[4];
  const f16* wsrc[4];
#pragma unroll
  for (int i = 0; i < 4; ++i) {
    int r = m0 + w * 32 + i * 8 + (lane >> 3);
    int ra = (r < mk) ? r : 0;
    int4 mt = meta[ra];
    xsrc[i] = xh + ((size_t)(mt.x + k) * BATCH + mt.y) * IDIM;
    hsrc[i] = hprev + (size_t)ra * HDIM;
    wsrc[i] = Wc + (size_t)(n0 + w * 32 + i * 8 + (lane >> 3)) * 1024;
  }
  const int koff = (lane & 7) * 8;

  f32x4 acc[4][4];
#pragma unroll
  for (int a = 0; a < 4; ++a)
#pragma unroll
    for (int bb = 0; bb < 4; ++bb) acc[a][bb] = (f32x4){0.f, 0.f, 0.f, 0.f};

  const int KB = FIRST ? 8 : 16;
  for (int kb = 0; kb < KB; ++kb) {
    __syncthreads();
#pragma unroll
    for (int i = 0; i < 4; ++i) {
      const f16* s;
      if (FIRST) s = xsrc[i] + kb * 64 + koff;
      else       s = (kb < 8) ? (xsrc[i] + kb * 64 + koff) : (hsrc[i] + (kb - 8) * 64 + koff);
      gload16(s, &At[w * 32 + i * 8][0]);
    }
#pragma unroll
    for (int i = 0; i < 4; ++i) gload16(wsrc[i] + kb * 64 + koff, &Bt[w * 32 + i * 8][0]);
    __syncthreads();

    const int lr = lane & 15;
    const int lk = (lane >> 4) * 8;
#pragma unroll
    for (int ks = 0; ks < 2; ++ks) {
      f16x8 af[4], bfr[4];
#pragma unroll
      for (int f = 0; f < 4; ++f) af[f] = *(const f16x8*)&At[wr * 64 + f * 16 + lr][ks * 32 + lk];
#pragma unroll
      for (int f = 0; f < 4; ++f) bfr[f] = *(const f16x8*)&Bt[wc * 64 + f * 16 + lr][ks * 32 + lk];
#pragma unroll
      for (int fm = 0; fm < 4; ++fm)
#pragma unroll
        for (int fn = 0; fn < 4; ++fn)
          acc[fm][fn] = __builtin_amdgcn_mfma_f32_16x16x32_f16(af[fm], bfr[fn], acc[fm][fn], 0, 0, 0);
    }
  }

  const int r15 = lane & 15;
  float bq[4];
#pragma unroll
  for (int q = 0; q < 4; ++q) bq[q] = biasp[n0 + wc * 64 + q * 16 + r15];
  const int j = ((n0 + wc * 64) >> 6) * 16 + r15;
  const size_t segoff = (size_t)T * BATCH * HDIM + (size_t)2 * BATCH * HDIM;

#pragma unroll
  for (int fm = 0; fm < 4; ++fm) {
#pragma unroll
    for (int reg = 0; reg < 4; ++reg) {
      int m = m0 + wr * 64 + fm * 16 + ((lane >> 4) << 2) + reg;
      if (m >= mk) continue;
      int4 mt = metaS[m - m0];
      float gi = acc[fm][0][reg] + bq[0];
      float gf = acc[fm][1][reg] + bq[1];
      float gg = acc[fm][2][reg] + bq[2];
      float go = acc[fm][3][reg] + bq[3];
      float iv = sigmoidf_(gi), fv = sigmoidf_(gf);
      float gv = tanhf_(gg), ov = sigmoidf_(go);
      float cp, hp;
      if (FIRST) { cp = 0.f; hp = 0.f; }
      else {
        cp = cst[(size_t)m * HDIM + j];
        hp = (float)hprev[(size_t)m * HDIM + j];
      }
      float cn = fv * cp + iv * gv;
      float hn = ov * tanhf_(cn);
      float hz = ZK * hp + (1.f - ZK) * hn;
      float cz = ZK * cp + (1.f - ZK) * cn;
      out[((size_t)(mt.x + k) * BATCH + mt.y) * HDIM + j] = hz;
      if (k == mt.w - 1) {
        out[segoff + ((size_t)mt.y * SEGS + mt.z) * HDIM + j] = hz;
      } else {
        hnext[(size_t)m * HDIM + j] = (f16)hz;
        cst[(size_t)m * HDIM + j] = cz;
      }
    }
  }
}

extern "C" void kernel_launch(void* const* d_in, const int* in_sizes, int n_in,
                              void* d_out, int out_size, void* d_ws, size_t ws_size,
                              hipStream_t stream) {
  const float* x = (const float*)d_in[0];
  const int* durs = (const int*)d_in[1];
  const float* Wih = (const float*)d_in[2];
  const float* Whh = (const float*)d_in[3];
  const float* bih = (const float*)d_in[4];
  const float* bhh = (const float*)d_in[5];
  float* out = (float*)d_out;
  const int T = in_sizes[0] / (BATCH * IDIM);

  char* ws = (char*)d_ws;
  size_t off = 0;
  auto alloc = [&](size_t bytes) {
    void* p = ws + off;
    off = (off + bytes + 255) & ~(size_t)255;
    return p;
  };
  f16* xh     = (f16*)alloc((size_t)T * BATCH * IDIM * 2);
  f16* Wc     = (f16*)alloc((size_t)NGATE * 1024 * 2);
  float* biasp= (float*)alloc((size_t)NGATE * 4);
  f16* hst0   = (f16*)alloc((size_t)SEGS * BATCH * HDIM * 2);
  f16* hst1   = (f16*)alloc((size_t)SEGS * BATCH * HDIM * 2);
  float* cst  = (float*)alloc((size_t)SEGS * BATCH * HDIM * 4);
  int4* meta  = (int4*)alloc((size_t)SEGS * BATCH * 16);
  int* Mk     = (int*)alloc(64);
  int* mel    = (int*)alloc(64);

  prep_kernel<<<1, 64, 0, stream>>>(durs, meta, Mk, mel);
  wprep_kernel<<<NGATE, 256, 0, stream>>>(Wih, Whh, bih, bhh, Wc, biasp);
  long n8 = (long)T * BATCH * IDIM / 8;
  xconv_kernel<<<2048, 256, 0, stream>>>(x, xh, n8);
  zero_kernel<<<T * BATCH + 128, 128, 0, stream>>>(out, mel, T);

  // head: k=0..7 on the 256^2 8-wave pipelined kernel
  dim3 hgrid(8, 32);  // x: N/256, y: M/256
  step256_kernel<true><<<hgrid, 512, 0, stream>>>(xh, Wc, biasp, hst0, hst1, cst, meta, Mk, out, T, 0);
  for (int k = 1; k < 8; ++k) {
    f16* hp = (k & 1) ? hst1 : hst0;
    f16* hn = (k & 1) ? hst0 : hst1;
    step256_kernel<false><<<hgrid, 512, 0, stream>>>(xh, Wc, biasp, hp, hn, cst, meta, Mk, out, T, k);
  }
  // tail: k=8..11 on the 128^2 kernel (more blocks for small Mk)
  dim3 sgrid(16, 64);  // x: N/128, y: M/128
  for (int k = 8; k < 12; ++k) {
    f16* hp = (k & 1) ? hst1 : hst0;
    f16* hn = (k & 1) ? hst0 : hst1;
    step_kernel<false><<<sgrid, 256, 0, stream>>>(xh, Wc, biasp, hp, hn, cst, meta, Mk, out, T, k);
  }
}